// Round 2
// baseline (262.200 us; speedup 1.0000x reference)
//
#include <hip/hip_runtime.h>

// Y_t = U^T * X_t * V  per token, via bf16 MFMA 16x16x32.
// v3: token-loop software pipeline.
//   - 512 blocks x 4 tokens/block (whole grid resident, 2 blocks/CU).
//   - Per token: convert prefetched X -> stage1 MFMA -> issue NEXT token's
//     x-loads -> write T^T to double-buffered LDS -> lgkm-only barrier
//     (x prefetch stays in flight across it) -> stage2 MFMA -> nt stores.
//   - y stored nontemporal: write-once data stays out of L3 so x stays cached.

typedef short bf16x8 __attribute__((ext_vector_type(8)));
typedef float f32x4  __attribute__((ext_vector_type(4)));

#define DIM   128
#define TP    136   // T^T LDS pitch (bf16): 272B rows, 16B-aligned, ~conflict-free
#define NTOK  2048
#define TPB   4     // tokens per block
#define GRID  (NTOK / TPB)

static __device__ __forceinline__ unsigned short f2bf(float f) {
    union { float f; unsigned u; } v; v.f = f;
    unsigned r = v.u + 0x7FFFu + ((v.u >> 16) & 1u);  // round-nearest-even
    return (unsigned short)(r >> 16);
}

// Build U/V bf16 fragment-swizzled copies in workspace (unchanged).
// Granule g in [0,2048) per matrix: g = (tile*4 + kk)*64 + lane.
// Granule holds 8 bf16: B[k][n] = src[k*128 + n] for n = tile*16 + (lane&15),
// k = kk*32 + (lane>>4)*8 + j, j=0..7. (For U this yields A[m=j1][k=i1] = U[i1*128+j1].)
__global__ void kron_prep_uv(const float* __restrict__ U,
                             const float* __restrict__ V,
                             unsigned short* __restrict__ swz) {
    int g = blockIdx.x * blockDim.x + threadIdx.x;   // 0..4095
    const float* src = (g < 2048) ? V : U;
    int gg   = g & 2047;
    int lane = gg & 63;
    int blk  = gg >> 6;
    int kk   = blk & 3;
    int tile = blk >> 2;
    int n  = tile * 16 + (lane & 15);
    int k0 = kk * 32 + (lane >> 4) * 8;
    bf16x8 v;
#pragma unroll
    for (int j = 0; j < 8; ++j)
        v[j] = (short)f2bf(src[(k0 + j) * DIM + n]);
    *(bf16x8*)(swz + (size_t)g * 8) = v;
}

__global__ __launch_bounds__(256, 2)
void kron_main(const float* __restrict__ x,
               const unsigned short* __restrict__ Vs,   // swizzled V (stage-1 B frags)
               const unsigned short* __restrict__ Us,   // swizzled U^T (stage-2 A frags)
               float* __restrict__ y) {
    __shared__ unsigned short Tt[2][DIM * TP];   // 2 x 34816 B double buffer

    const int tid   = threadIdx.x;
    const int lane  = tid & 63;
    const int wave  = tid >> 6;     // owns X rows / Y rows [32*wave, 32*wave+32)
    const int m16   = lane & 15;
    const int q     = lane >> 4;
    const int tbase = blockIdx.x * TPB;

    // ---- hoist U^T fragments (reused for every token) ----
    bf16x8 ua[2][4];
#pragma unroll
    for (int mt = 0; mt < 2; ++mt)
#pragma unroll
        for (int kk = 0; kk < 4; ++kk)
            ua[mt][kk] = *(const bf16x8*)(Us + (size_t)(((wave * 2 + mt) * 4 + kk) * 64 + lane) * 8);

    // ---- prologue: issue x loads for token 0 ----
    float4 raw[16];
    {
        const float* xp = x + (size_t)tbase * (DIM * DIM);
#pragma unroll
        for (int mt = 0; mt < 2; ++mt) {
            const float* rp = xp + (wave * 32 + mt * 16 + m16) * DIM + q * 8;
#pragma unroll
            for (int kk = 0; kk < 4; ++kk) {
                raw[(mt * 4 + kk) * 2 + 0] = *(const float4*)(rp + kk * 32);
                raw[(mt * 4 + kk) * 2 + 1] = *(const float4*)(rp + kk * 32 + 4);
            }
        }
    }

    for (int it = 0; it < TPB; ++it) {
        // ---- convert prefetched fp32 -> bf16 A-fragments ----
        bf16x8 af[2][4];
#pragma unroll
        for (int mt = 0; mt < 2; ++mt)
#pragma unroll
            for (int kk = 0; kk < 4; ++kk) {
                const float4 a = raw[(mt * 4 + kk) * 2 + 0];
                const float4 b = raw[(mt * 4 + kk) * 2 + 1];
                bf16x8 v;
                v[0] = (short)f2bf(a.x); v[1] = (short)f2bf(a.y);
                v[2] = (short)f2bf(a.z); v[3] = (short)f2bf(a.w);
                v[4] = (short)f2bf(b.x); v[5] = (short)f2bf(b.y);
                v[6] = (short)f2bf(b.z); v[7] = (short)f2bf(b.w);
                af[mt][kk] = v;
            }

        // ---- stage 1: T[32w..][:] = X_rows @ V ----
        f32x4 acc[2][8] = {};
#pragma unroll
        for (int kk = 0; kk < 4; ++kk)
#pragma unroll
            for (int nt = 0; nt < 8; ++nt) {
                const bf16x8 bv = *(const bf16x8*)(Vs + (size_t)((nt * 4 + kk) * 64 + lane) * 8);
#pragma unroll
                for (int mt = 0; mt < 2; ++mt)
                    acc[mt][nt] = __builtin_amdgcn_mfma_f32_16x16x32_bf16(af[mt][kk], bv, acc[mt][nt], 0, 0, 0);
            }

        // ---- issue next token's x loads (in flight across barrier + stage 2) ----
        if (it + 1 < TPB) {
            const float* xp = x + (size_t)(tbase + it + 1) * (DIM * DIM);
#pragma unroll
            for (int mt = 0; mt < 2; ++mt) {
                const float* rp = xp + (wave * 32 + mt * 16 + m16) * DIM + q * 8;
#pragma unroll
                for (int kk = 0; kk < 4; ++kk) {
                    raw[(mt * 4 + kk) * 2 + 0] = *(const float4*)(rp + kk * 32);
                    raw[(mt * 4 + kk) * 2 + 1] = *(const float4*)(rp + kk * 32 + 4);
                }
            }
        }

        // ---- write own T^T slice (bf16): Tt[buf][j2][i1] ----
        unsigned short* tt = &Tt[it & 1][0];
#pragma unroll
        for (int mt = 0; mt < 2; ++mt)
#pragma unroll
            for (int nt = 0; nt < 8; ++nt) {
                const int j2 = nt * 16 + m16;
                const int i1 = wave * 32 + mt * 16 + q * 4;
                unsigned p0 = (unsigned)f2bf(acc[mt][nt][0]) | ((unsigned)f2bf(acc[mt][nt][1]) << 16);
                unsigned p1 = (unsigned)f2bf(acc[mt][nt][2]) | ((unsigned)f2bf(acc[mt][nt][3]) << 16);
                uint2 w; w.x = p0; w.y = p1;
                *(uint2*)&tt[j2 * TP + i1] = w;
            }

        // ---- barrier WITHOUT vmcnt drain: LDS writes visible, x prefetch live ----
        asm volatile("s_waitcnt lgkmcnt(0)" ::: "memory");
        __builtin_amdgcn_s_barrier();

        // ---- stage 2: Y[32w..][:] = U^T_rows @ T (reuse acc registers) ----
#pragma unroll
        for (int mt = 0; mt < 2; ++mt)
#pragma unroll
            for (int nt = 0; nt < 8; ++nt)
                acc[mt][nt] = (f32x4){0.f, 0.f, 0.f, 0.f};
#pragma unroll
        for (int kk = 0; kk < 4; ++kk)
#pragma unroll
            for (int nt = 0; nt < 8; ++nt) {
                const bf16x8 tb = *(const bf16x8*)&tt[(nt * 16 + m16) * TP + kk * 32 + q * 8];
#pragma unroll
                for (int mt = 0; mt < 2; ++mt)
                    acc[mt][nt] = __builtin_amdgcn_mfma_f32_16x16x32_bf16(ua[mt][kk], tb, acc[mt][nt], 0, 0, 0);
            }

        // ---- store Y (fp32, nontemporal: keep x resident in L3) ----
        float* yp = y + (size_t)(tbase + it) * (DIM * DIM);
#pragma unroll
        for (int mt = 0; mt < 2; ++mt)
#pragma unroll
            for (int r = 0; r < 4; ++r) {
                const int row = wave * 32 + mt * 16 + q * 4 + r;
#pragma unroll
                for (int nt = 0; nt < 8; ++nt)
                    __builtin_nontemporal_store(acc[mt][nt][r], &yp[row * DIM + nt * 16 + m16]);
            }
    }
}

extern "C" void kernel_launch(void* const* d_in, const int* in_sizes, int n_in,
                              void* d_out, int out_size, void* d_ws, size_t ws_size,
                              hipStream_t stream) {
    const float* x = (const float*)d_in[0];
    const float* U = (const float*)d_in[1];
    const float* V = (const float*)d_in[2];
    float*       y = (float*)d_out;

    unsigned short* swz = (unsigned short*)d_ws;   // [0,16384): V frags; [16384,32768): U frags
    kron_prep_uv<<<16, 256, 0, stream>>>(U, V, swz);
    kron_main<<<GRID, 256, 0, stream>>>(x, swz, swz + 2048 * 8, y);
}